// Round 1
// baseline (705.223 us; speedup 1.0000x reference)
//
#include <hip/hip_runtime.h>
#include <hip/hip_bf16.h>

typedef _Float16 f16;
typedef f16 f16x4 __attribute__((ext_vector_type(4)));
typedef f16 f16x8 __attribute__((ext_vector_type(8)));
typedef float f32x4 __attribute__((ext_vector_type(4)));

#define BB 32
#define NN 1024
#define HH 128
#define ROWS (BB*NN)          // 32768
#define EPS 1e-5f

__device__ __forceinline__ f16 f2h(float x) { return (f16)x; }

// ---------------------------------------------------------------------------
// Prep kernel: block ranges do different jobs.
//  [0,1024)    : mask_h[j][i] (f16 0/1) + deg[j]
//  [1024,2048) : maskT[i][j] (f32) via 32x32 LDS transpose
//  [2048,4096) : node f32 -> f16 into upd_in[row][0..127]
//  4096        : pack Wh f16[128][128], Wupd f16[128][256], We f32[128][3], zero sums[256]
//  [4097,4129) : zero e_agg (32*1024*3 f32)
// ---------------------------------------------------------------------------
__global__ __launch_bounds__(256) void prep_k(
    const float* __restrict__ node, const int* __restrict__ adj,
    const float* __restrict__ W_msg, const float* __restrict__ W_upd,
    f16* __restrict__ mask_h, float* __restrict__ maskT, float* __restrict__ deg,
    f16* __restrict__ upd_in, f16* __restrict__ Wh, f16* __restrict__ Wupd,
    float* __restrict__ We, float* __restrict__ e_agg, float* __restrict__ sums)
{
  const int blk = blockIdx.x, t = threadIdx.x;
  if (blk < 1024) {
    const int j = blk;
    float d = 0.f;
    for (int i = t; i < NN; i += 256) {
      const int a = (adj[j*NN + i] > 0) ? 1 : 0;
      mask_h[j*NN + i] = a ? (f16)1.0f : (f16)0.0f;
      d += (float)a;
    }
    __shared__ float sh[256];
    sh[t] = d;
    for (int s = 128; s > 0; s >>= 1) {
      __syncthreads();
      if (t < s) sh[t] += sh[t + s];
    }
    __syncthreads();
    if (t == 0) deg[j] = sh[0];
  } else if (blk < 2048) {
    const int bi = (blk - 1024) & 31, bj = (blk - 1024) >> 5;
    __shared__ float tile[32][33];
    const int lx = t & 31, ly0 = t >> 5;   // 32 x 8 threads
    for (int ly = ly0; ly < 32; ly += 8)
      tile[ly][lx] = (adj[(bj*32 + ly)*NN + bi*32 + lx] > 0) ? 1.0f : 0.0f;
    __syncthreads();
    for (int ly = ly0; ly < 32; ly += 8)
      maskT[(long)(bi*32 + ly)*NN + bj*32 + lx] = tile[lx][ly];
  } else if (blk < 4096) {
    // node conversion: 1048576 float4s over 2048 blocks x 256 thr x 2
    const int base = (blk - 2048) * 512 + t;
    #pragma unroll
    for (int rep = 0; rep < 2; rep++) {
      const int idx = base + rep * 256;
      const float4 v = ((const float4*)node)[idx];
      f16x4 hv; hv[0] = f2h(v.x); hv[1] = f2h(v.y); hv[2] = f2h(v.z); hv[3] = f2h(v.w);
      const int row = idx >> 5;              // 32 float4 per 128-col row
      const int col = (idx & 31) << 2;
      *(f16x4*)&upd_in[(long)row*256 + col] = hv;
    }
  } else if (blk == 4096) {
    for (int idx = t; idx < HH*HH; idx += 256) {        // Wh[o][h]
      const int o = idx >> 7, h = idx & 127;
      Wh[idx] = f2h(W_msg[o*131 + h]);
    }
    for (int idx = t; idx < HH*256; idx += 256) {       // Wupd[o][k]
      const int o = idx >> 8, k = idx & 255;
      Wupd[idx] = f2h(W_upd[o*256 + k]);
    }
    for (int idx = t; idx < HH*3; idx += 256) {         // We[o][c]
      const int o = idx / 3, c = idx % 3;
      We[idx] = W_msg[o*131 + 128 + c];
    }
    if (t < 256) sums[t] = 0.f;
  } else {
    const int base = (blk - 4097) * 3072 + t;
    #pragma unroll
    for (int r = 0; r < 12; r++) e_agg[base + r*256] = 0.f;
  }
}

// ---------------------------------------------------------------------------
// e_agg[b][j][c] = sum_i E[b][i][j][c] * maskT[i][j]
// grid (8 jtiles of 128, 2 i-halves, 32 batches), 384 threads: t -> (j_loc=t/3, c=t%3)
// ---------------------------------------------------------------------------
__global__ __launch_bounds__(384) void eagg_k(
    const float* __restrict__ E, const float* __restrict__ maskT,
    float* __restrict__ e_agg)
{
  const int jt = blockIdx.x << 7;
  const int ih = blockIdx.y << 9;     // 0 or 512
  const int b  = blockIdx.z;
  const int t  = threadIdx.x;
  const int jl = t / 3, c = t % 3;
  const int j  = jt + jl;
  const float* Ep = E + (long)b*3145728 + (long)ih*3072 + jt*3 + t;
  const float* Mp = maskT + (long)ih*NN + j;
  float acc = 0.f;
  for (int i0 = 0; i0 < 512; i0 += 8) {
    float ev[8], mv[8];
    #pragma unroll
    for (int u = 0; u < 8; u++) ev[u] = Ep[(long)(i0 + u)*3072];
    #pragma unroll
    for (int u = 0; u < 8; u++) mv[u] = Mp[(long)(i0 + u)*NN];
    #pragma unroll
    for (int u = 0; u < 8; u++) acc = fmaf(mv[u], ev[u], acc);
  }
  atomicAdd(&e_agg[((long)b*NN + j)*3 + c], acc);
}

// ---------------------------------------------------------------------------
// MFMA GEMM, B^T layout: C[m][n] = sum_k A[m][k] * B[n][k]   (both k-contiguous)
// block tile 128x128, 256 thr = 4 waves (2x2 of 64x64), BK=32, f16 16x16x32 MFMA.
// MODE 0: h_part_T  (A=Wh[128][128], B=upd_in rows (b,i) k=0..127) -> f16 [b][o][i]
// MODE 1: messages  (A=mask_h[1024][1024], B=h_part_T[b][o][i]) + deg*b_msg +
//          e_agg.We -> f16 into upd_in[row][128+o]
// MODE 2: updated   (A=upd_in[32768][256], B=Wupd[128][256]) relu(+b_upd) -> f32
// ---------------------------------------------------------------------------
template<int MODE>
__global__ __launch_bounds__(256) void gemm_bt_k(
    const f16* __restrict__ Ag, long aBatch, int lda,
    const f16* __restrict__ Bg, long bBatch, int ldb,
    int K, void* __restrict__ outp,
    const float* __restrict__ deg, const float* __restrict__ b_msg,
    const float* __restrict__ e_agg, const float* __restrict__ We,
    const float* __restrict__ b_upd)
{
  const int mt = blockIdx.x, nt = blockIdx.y, bb = blockIdx.z;
  const f16* Ab = Ag + (long)bb*aBatch + (long)mt*128*lda;
  const f16* Bb = Bg + (long)bb*bBatch + (long)nt*128*ldb;
  __shared__ f16 As[128*32];
  __shared__ f16 Bs[128*32];
  const int tid  = threadIdx.x;
  const int lane = tid & 63;
  const int wave = tid >> 6;
  const int wm = (wave & 1) << 6, wn = (wave >> 1) << 6;

  f32x4 acc[4][4];
  #pragma unroll
  for (int i = 0; i < 4; i++)
    #pragma unroll
    for (int j = 0; j < 4; j++)
      #pragma unroll
      for (int r = 0; r < 4; r++) acc[i][j][r] = 0.f;

  for (int k0 = 0; k0 < K; k0 += 32) {
    #pragma unroll
    for (int p = 0; p < 2; p++) {
      const int q = (p << 8) + tid;       // 0..511
      const int row = q >> 2, ks = (q & 3) << 3;
      *(uint4*)&As[(row << 5) + ks] = *(const uint4*)&Ab[(long)row*lda + k0 + ks];
      *(uint4*)&Bs[(row << 5) + ks] = *(const uint4*)&Bb[(long)row*ldb + k0 + ks];
    }
    __syncthreads();
    f16x8 af[4], bf[4];
    #pragma unroll
    for (int i = 0; i < 4; i++) {
      af[i] = *(const f16x8*)&As[((wm + (i << 4) + (lane & 15)) << 5) + ((lane >> 4) << 3)];
      bf[i] = *(const f16x8*)&Bs[((wn + (i << 4) + (lane & 15)) << 5) + ((lane >> 4) << 3)];
    }
    #pragma unroll
    for (int i = 0; i < 4; i++)
      #pragma unroll
      for (int j = 0; j < 4; j++)
        acc[i][j] = __builtin_amdgcn_mfma_f32_16x16x32_f16(af[i], bf[j], acc[i][j], 0, 0, 0);
    __syncthreads();
  }

  const int rb = (lane >> 4) << 2, cb = lane & 15;
  if (MODE == 0) {
    f16* out = (f16*)outp + (long)bb * (HH*NN);
    #pragma unroll
    for (int i = 0; i < 4; i++)
      #pragma unroll
      for (int r = 0; r < 4; r++) {
        const int gm = (mt << 7) + wm + (i << 4) + rb + r;       // o
        #pragma unroll
        for (int j = 0; j < 4; j++) {
          const int gn = (nt << 7) + wn + (j << 4) + cb;         // i
          out[(long)gm*NN + gn] = f2h(acc[i][j][r]);
        }
      }
  } else if (MODE == 1) {
    f16* out = (f16*)outp;
    #pragma unroll
    for (int i = 0; i < 4; i++)
      #pragma unroll
      for (int r = 0; r < 4; r++) {
        const int gm = (mt << 7) + wm + (i << 4) + rb + r;       // j
        const float dg = deg[gm];
        const long eb = ((long)bb*NN + gm)*3;
        const float e0 = e_agg[eb], e1 = e_agg[eb+1], e2 = e_agg[eb+2];
        #pragma unroll
        for (int j = 0; j < 4; j++) {
          const int gn = wn + (j << 4) + cb;                     // o
          const float v = acc[i][j][r] + dg*b_msg[gn]
                        + e0*We[gn*3] + e1*We[gn*3+1] + e2*We[gn*3+2];
          out[((long)bb*NN + gm)*256 + 128 + gn] = f2h(v);
        }
      }
  } else {
    float* out = (float*)outp;
    #pragma unroll
    for (int i = 0; i < 4; i++)
      #pragma unroll
      for (int r = 0; r < 4; r++) {
        const int gm = (mt << 7) + wm + (i << 4) + rb + r;       // flat row
        #pragma unroll
        for (int j = 0; j < 4; j++) {
          const int gn = wn + (j << 4) + cb;                     // o
          const float v = acc[i][j][r] + b_upd[gn];
          out[(long)gm*HH + gn] = fmaxf(v, 0.f);
        }
      }
  }
}

// ---------------------------------------------------------------------------
// Per-feature sums over 32768 rows: sums[0..127]=sum, sums[128..255]=sum of sq
// ---------------------------------------------------------------------------
__global__ __launch_bounds__(256) void stats_k(const float* __restrict__ upd,
                                               float* __restrict__ sums)
{
  const int t = threadIdx.x, o = t & 127, half = t >> 7;
  const long base = (long)blockIdx.x * 128;
  float s = 0.f, q = 0.f;
  for (int r = half; r < 128; r += 2) {
    const float v = upd[(base + r)*HH + o];
    s += v; q += v*v;
  }
  __shared__ float shs[256], shq[256];
  shs[t] = s; shq[t] = q;
  __syncthreads();
  if (t < 128) {
    atomicAdd(&sums[t],       shs[t] + shs[t + 128]);
    atomicAdd(&sums[128 + t], shq[t] + shq[t + 128]);
  }
}

__global__ __launch_bounds__(256) void final_k(const float* __restrict__ upd,
    const float* __restrict__ node, const float* __restrict__ sums,
    const float* __restrict__ gamma, const float* __restrict__ beta,
    float* __restrict__ out)
{
  const long idx = (long)blockIdx.x*256 + threadIdx.x;   // float4 index
  const float4 u  = ((const float4*)upd)[idx];
  const float4 nd = ((const float4*)node)[idx];
  const int ob = (idx & 31) << 2;
  const float inv = 1.0f/32768.0f;
  float4 res;
  #pragma unroll
  for (int c = 0; c < 4; c++) {
    const float m  = sums[ob + c]*inv;
    const float va = sums[128 + ob + c]*inv - m*m;
    const float sc = rsqrtf(va + EPS)*gamma[ob + c];
    ((float*)&res)[c] = (((const float*)&u)[c] - m)*sc + beta[ob + c]
                      + ((const float*)&nd)[c];
  }
  ((float4*)out)[idx] = res;
}

// ---------------------------------------------------------------------------
extern "C" void kernel_launch(void* const* d_in, const int* in_sizes, int n_in,
                              void* d_out, int out_size, void* d_ws, size_t ws_size,
                              hipStream_t stream) {
  const float* node  = (const float*)d_in[0];
  const float* E     = (const float*)d_in[1];
  const int*   adj   = (const int*)  d_in[2];
  const float* W_msg = (const float*)d_in[3];
  const float* b_msg = (const float*)d_in[4];
  const float* W_upd = (const float*)d_in[5];
  const float* b_upd = (const float*)d_in[6];
  const float* gamma = (const float*)d_in[7];
  const float* beta  = (const float*)d_in[8];
  float* out = (float*)d_out;

  char* p = (char*)d_ws;
  auto alloc = [&](size_t n) { void* r = (void*)p; p += (n + 255) & ~(size_t)255; return r; };
  f16*   upd_in   = (f16*)  alloc((size_t)ROWS*256*2);   // [row][0..127]=node, [128..255]=messages
  f16*   h_part_T = (f16*)  alloc((size_t)BB*HH*NN*2);   // [b][o][i]
  f16*   mask_h   = (f16*)  alloc((size_t)NN*NN*2);      // [j][i]
  float* maskT    = (float*)alloc((size_t)NN*NN*4);      // [i][j]
  float* updated  = (float*)alloc((size_t)ROWS*HH*4);    // relu output, f32
  float* e_agg    = (float*)alloc((size_t)BB*NN*3*4);
  f16*   Wh       = (f16*)  alloc((size_t)HH*HH*2);
  f16*   Wupd     = (f16*)  alloc((size_t)HH*256*2);
  float* We       = (float*)alloc((size_t)HH*3*4);
  float* deg      = (float*)alloc((size_t)NN*4);
  float* sums     = (float*)alloc((size_t)256*4);

  prep_k<<<4129, 256, 0, stream>>>(node, adj, W_msg, W_upd, mask_h, maskT, deg,
                                   upd_in, Wh, Wupd, We, e_agg, sums);

  // h_part_T[b][o][i]: A=Wh (M=128), B=upd_in node cols (N=1024 per batch), K=128
  gemm_bt_k<0><<<dim3(1, 8, BB), 256, 0, stream>>>(
      Wh, 0, HH, upd_in, (long)NN*256, 256, HH, h_part_T,
      nullptr, nullptr, nullptr, nullptr, nullptr);

  eagg_k<<<dim3(8, 2, BB), 384, 0, stream>>>(E, maskT, e_agg);

  // messages: A=mask_h (M=1024), B=h_part_T[b] (N=128), K=1024
  gemm_bt_k<1><<<dim3(8, 1, BB), 256, 0, stream>>>(
      mask_h, 0, NN, h_part_T, (long)HH*NN, NN, NN, upd_in,
      deg, b_msg, e_agg, We, nullptr);

  // updated: A=upd_in (M=32768), B=Wupd (N=128), K=256
  gemm_bt_k<2><<<dim3(256, 1, 1), 256, 0, stream>>>(
      upd_in, 0, 256, Wupd, 0, 256, 256, updated,
      nullptr, nullptr, nullptr, nullptr, b_upd);

  stats_k<<<256, 256, 0, stream>>>(updated, sums);
  final_k<<<4096, 256, 0, stream>>>(updated, node, sums, gamma, beta, out);
}

// Round 2
// 653.565 us; speedup vs baseline: 1.0790x; 1.0790x over previous
//
#include <hip/hip_runtime.h>
#include <hip/hip_bf16.h>

typedef _Float16 f16;
typedef f16 f16x4 __attribute__((ext_vector_type(4)));
typedef f16 f16x8 __attribute__((ext_vector_type(8)));
typedef float f32x4 __attribute__((ext_vector_type(4)));

#define BB 32
#define NN 1024
#define HH 128
#define ROWS (BB*NN)          // 32768
#define EPS 1e-5f

__device__ __forceinline__ f16 f2h(float x) { return (f16)x; }

// ---------------------------------------------------------------------------
// prep0: tiny pack/zero kernel (7 blocks x 256)
//  blk0: Wh f16[128][128] from W_msg (stride 131)
//  blk1: Wupd f16[128][256] from W_upd (contiguous)
//  blk2: We f32[128][3], zero sums[256], zero deg[1024]
//  blk3..6: zero e_agg (32*1024*3 floats, quarter each)
// ---------------------------------------------------------------------------
__global__ __launch_bounds__(256) void prep0_k(
    const float* __restrict__ W_msg, const float* __restrict__ W_upd,
    f16* __restrict__ Wh, f16* __restrict__ Wupd, float* __restrict__ We,
    float* __restrict__ e_agg, float* __restrict__ deg, float* __restrict__ sums)
{
  const int blk = blockIdx.x, t = threadIdx.x;
  if (blk == 0) {
    for (int idx = t; idx < HH*HH; idx += 256) {
      const int o = idx >> 7, h = idx & 127;
      Wh[idx] = f2h(W_msg[o*131 + h]);
    }
  } else if (blk == 1) {
    for (int idx = t; idx < HH*256; idx += 256)
      Wupd[idx] = f2h(W_upd[idx]);
  } else if (blk == 2) {
    for (int idx = t; idx < HH*3; idx += 256)
      We[idx] = W_msg[(idx/3)*131 + 128 + (idx % 3)];
    if (t < 256) sums[t] = 0.f;
    for (int idx = t; idx < NN; idx += 256) deg[idx] = 0.f;
  } else {
    const int base = (blk - 3) * 24576 + t;
    #pragma unroll
    for (int r = 0; r < 96; r++) e_agg[base + r*256] = 0.f;
  }
}

// ---------------------------------------------------------------------------
// Phase B megakernel: 1280 blocks x 256.
//  blk [0,256): gemm0 — h_part_T[b][o][i] = sum_h Wh[o][h]*node[b,i,h]
//               (A = Wh f16, B = node f32 converted during staging)
//  blk [256,1280): eagg — e_agg[b][j][c] += sum_i E[b,i,j,c]*(adj[j,i]>0)
//               b==0 blocks also accumulate deg[j].
// ---------------------------------------------------------------------------
__global__ __launch_bounds__(256) void phaseB_k(
    const float* __restrict__ node, const float* __restrict__ E,
    const int* __restrict__ adj, const f16* __restrict__ Wh,
    f16* __restrict__ h_part_T, float* __restrict__ e_agg,
    float* __restrict__ deg)
{
  __shared__ f16 As[128*32];
  __shared__ f16 Bs[128*32];
  const int tid = threadIdx.x;

  if (blockIdx.x >= 256) {
    // ---- eagg path ----
    const int e  = blockIdx.x - 256;        // 0..1023
    const int bb = e >> 5;
    const int r5 = e & 31;
    const int jt = r5 & 3;                  // 4 j-tiles of 256
    const int ih = r5 >> 2;                 // 8 i-chunks of 128
    const int j  = (jt << 8) + tid;
    const int i0 = ih << 7;
    const float* Ep = E + (long)bb*3145728 + (long)i0*3072 + (long)j*3;
    const int*   Ap = adj + (long)j*NN + i0;
    float a0 = 0.f, a1 = 0.f, a2 = 0.f, dc = 0.f;
    for (int ii = 0; ii < 128; ii += 8) {
      const int4 m0 = *(const int4*)(Ap + ii);
      const int4 m1 = *(const int4*)(Ap + ii + 4);
      float ev[8][3];
      #pragma unroll
      for (int v = 0; v < 8; v++) {
        const float* q = Ep + (long)(ii + v)*3072;
        ev[v][0] = q[0]; ev[v][1] = q[1]; ev[v][2] = q[2];
      }
      const int mm[8] = {m0.x, m0.y, m0.z, m0.w, m1.x, m1.y, m1.z, m1.w};
      #pragma unroll
      for (int v = 0; v < 8; v++) {
        const float m = (mm[v] > 0) ? 1.f : 0.f;
        a0 = fmaf(m, ev[v][0], a0);
        a1 = fmaf(m, ev[v][1], a1);
        a2 = fmaf(m, ev[v][2], a2);
        dc += m;
      }
    }
    const long eb = ((long)bb*NN + j)*3;
    atomicAdd(&e_agg[eb],     a0);
    atomicAdd(&e_agg[eb + 1], a1);
    atomicAdd(&e_agg[eb + 2], a2);
    if (bb == 0) atomicAdd(&deg[j], dc);
    return;
  }

  // ---- gemm0 path: M=128 (o), N=128 tile (i), K=128 ----
  const int g  = blockIdx.x;
  const int nt = g & 7, bb = g >> 3;
  const int nbase = nt << 7;                // i-tile base within batch
  const int lane = tid & 63, wave = tid >> 6;
  const int wm = (wave & 1) << 6, wn = (wave >> 1) << 6;

  f32x4 acc[2][4];
  #pragma unroll
  for (int i = 0; i < 2; i++)
    #pragma unroll
    for (int j = 0; j < 4; j++)
      #pragma unroll
      for (int r = 0; r < 4; r++) acc[i][j][r] = 0.f;
  // NOTE: M=128 -> each wave covers 64 rows (wm) -> 4 i-frags; keep 4x4 shape:
  f32x4 acc2[2][4];
  #pragma unroll
  for (int i = 0; i < 2; i++)
    #pragma unroll
    for (int j = 0; j < 4; j++)
      #pragma unroll
      for (int r = 0; r < 4; r++) acc2[i][j][r] = 0.f;

  for (int k0 = 0; k0 < HH; k0 += 32) {
    // A: Wh f16 128x32 (512 uint4, 2/thread)
    #pragma unroll
    for (int p = 0; p < 2; p++) {
      const int q = (p << 8) + tid;
      const int row = q >> 2, ks = (q & 3) << 3;
      *(uint4*)&As[(row << 5) + ks] = *(const uint4*)&Wh[(long)row*HH + k0 + ks];
    }
    // B: node f32 -> f16, 128x32 (1024 float4, 4/thread)
    #pragma unroll
    for (int p = 0; p < 4; p++) {
      const int q = (p << 8) + tid;
      const int row = q >> 3, kc = (q & 7) << 2;
      const float4 v = *(const float4*)&node[(long)((bb << 10) + nbase + row)*HH + k0 + kc];
      f16x4 hv; hv[0] = f2h(v.x); hv[1] = f2h(v.y); hv[2] = f2h(v.z); hv[3] = f2h(v.w);
      *(f16x4*)&Bs[(row << 5) + kc] = hv;
    }
    __syncthreads();
    f16x8 af[4], bf[4];
    #pragma unroll
    for (int i = 0; i < 4; i++) {
      af[i] = *(const f16x8*)&As[((wm + (i << 4) + (lane & 15)) << 5) + ((lane >> 4) << 3)];
      bf[i] = *(const f16x8*)&Bs[((wn + (i << 4) + (lane & 15)) << 5) + ((lane >> 4) << 3)];
    }
    #pragma unroll
    for (int i = 0; i < 2; i++)
      #pragma unroll
      for (int j = 0; j < 4; j++) {
        acc[i][j]  = __builtin_amdgcn_mfma_f32_16x16x32_f16(af[i],     bf[j], acc[i][j],  0, 0, 0);
        acc2[i][j] = __builtin_amdgcn_mfma_f32_16x16x32_f16(af[i + 2], bf[j], acc2[i][j], 0, 0, 0);
      }
    __syncthreads();
  }

  f16* out = h_part_T + (long)bb * (HH*NN);
  const int rb = (lane >> 4) << 2, cb = lane & 15;
  #pragma unroll
  for (int i = 0; i < 4; i++)
    #pragma unroll
    for (int r = 0; r < 4; r++) {
      const int gm = wm + (i << 4) + rb + r;                    // o
      #pragma unroll
      for (int j = 0; j < 4; j++) {
        const int gn = nbase + wn + (j << 4) + cb;              // i
        const float v = (i < 2) ? acc[i][j][r] : acc2[i - 2][j][r];
        out[(long)gm*NN + gn] = f2h(v);
      }
    }
}

// ---------------------------------------------------------------------------
// gemm1: messages[b,j,o] = sum_i mask[j,i]*h_part_T[b][o][i] + deg[j]*b_msg[o]
//        + e_agg[b,j,:]·We[o,:]   -> msgs f16 [b*1024+j][o]
// A staged from adj (int -> 0/1 f16), B = h_part_T. grid (8 mt, 1, 32 b).
// ---------------------------------------------------------------------------
__global__ __launch_bounds__(256) void gemm1_k(
    const int* __restrict__ adj, const f16* __restrict__ hp,
    const float* __restrict__ deg, const float* __restrict__ b_msg,
    const float* __restrict__ e_agg, const float* __restrict__ We,
    f16* __restrict__ msgs)
{
  const int mt = blockIdx.x, bb = blockIdx.z;
  const int jb = mt << 7;
  __shared__ f16 As[128*32];
  __shared__ f16 Bs[128*32];
  const int tid = threadIdx.x, lane = tid & 63, wave = tid >> 6;
  const int wm = (wave & 1) << 6, wn = (wave >> 1) << 6;

  f32x4 acc[4][4];
  #pragma unroll
  for (int i = 0; i < 4; i++)
    #pragma unroll
    for (int j = 0; j < 4; j++)
      #pragma unroll
      for (int r = 0; r < 4; r++) acc[i][j][r] = 0.f;

  for (int k0 = 0; k0 < NN; k0 += 32) {
    // A: adj ints -> 0/1 f16, 128x32 (1024 int4, 4/thread)
    #pragma unroll
    for (int p = 0; p < 4; p++) {
      const int q = (p << 8) + tid;
      const int row = q >> 3, kc = (q & 7) << 2;
      const int4 m = *(const int4*)&adj[(long)(jb + row)*NN + k0 + kc];
      f16x4 hv;
      hv[0] = (m.x > 0) ? (f16)1.0f : (f16)0.0f;
      hv[1] = (m.y > 0) ? (f16)1.0f : (f16)0.0f;
      hv[2] = (m.z > 0) ? (f16)1.0f : (f16)0.0f;
      hv[3] = (m.w > 0) ? (f16)1.0f : (f16)0.0f;
      *(f16x4*)&As[(row << 5) + kc] = hv;
    }
    // B: h_part_T f16 128x32 (512 uint4, 2/thread)
    #pragma unroll
    for (int p = 0; p < 2; p++) {
      const int q = (p << 8) + tid;
      const int row = q >> 2, ks = (q & 3) << 3;
      *(uint4*)&Bs[(row << 5) + ks] =
          *(const uint4*)&hp[(long)bb*(HH*NN) + (long)row*NN + k0 + ks];
    }
    __syncthreads();
    f16x8 af[4], bf[4];
    #pragma unroll
    for (int i = 0; i < 4; i++) {
      af[i] = *(const f16x8*)&As[((wm + (i << 4) + (lane & 15)) << 5) + ((lane >> 4) << 3)];
      bf[i] = *(const f16x8*)&Bs[((wn + (i << 4) + (lane & 15)) << 5) + ((lane >> 4) << 3)];
    }
    #pragma unroll
    for (int i = 0; i < 4; i++)
      #pragma unroll
      for (int j = 0; j < 4; j++)
        acc[i][j] = __builtin_amdgcn_mfma_f32_16x16x32_f16(af[i], bf[j], acc[i][j], 0, 0, 0);
    __syncthreads();
  }

  const int rb = (lane >> 4) << 2, cb = lane & 15;
  #pragma unroll
  for (int i = 0; i < 4; i++)
    #pragma unroll
    for (int r = 0; r < 4; r++) {
      const int gm = jb + wm + (i << 4) + rb + r;               // j
      const float dg = deg[gm];
      const long eb = ((long)bb*NN + gm)*3;
      const float e0 = e_agg[eb], e1 = e_agg[eb+1], e2 = e_agg[eb+2];
      #pragma unroll
      for (int j = 0; j < 4; j++) {
        const int gn = wn + (j << 4) + cb;                      // o
        const float v = acc[i][j][r] + dg*b_msg[gn]
                      + e0*We[gn*3] + e1*We[gn*3+1] + e2*We[gn*3+2];
        msgs[((long)bb*NN + gm)*HH + gn] = f2h(v);
      }
    }
}

// ---------------------------------------------------------------------------
// gemm2: updated[row][o] = relu(sum_k concat(node,msgs)[row][k]*Wupd[o][k] + b_upd[o])
// + per-column sum/sumsq atomics into sums[256]. grid 256 (row-tiles).
// ---------------------------------------------------------------------------
__global__ __launch_bounds__(256) void gemm2_k(
    const float* __restrict__ node, const f16* __restrict__ msgs,
    const f16* __restrict__ Wupd, const float* __restrict__ b_upd,
    f16* __restrict__ upd, float* __restrict__ sums)
{
  const int mt = blockIdx.x;
  const int rowb = mt << 7;
  __shared__ f16 As[128*32];
  __shared__ f16 Bs[128*32];
  __shared__ float colS[128], colQ[128];
  const int tid = threadIdx.x, lane = tid & 63, wave = tid >> 6;
  const int wm = (wave & 1) << 6, wn = (wave >> 1) << 6;
  if (tid < 128) { colS[tid] = 0.f; colQ[tid] = 0.f; }

  f32x4 acc[4][4];
  #pragma unroll
  for (int i = 0; i < 4; i++)
    #pragma unroll
    for (int j = 0; j < 4; j++)
      #pragma unroll
      for (int r = 0; r < 4; r++) acc[i][j][r] = 0.f;

  for (int k0 = 0; k0 < 256; k0 += 32) {
    if (k0 < HH) {
      // A from node f32 -> f16
      #pragma unroll
      for (int p = 0; p < 4; p++) {
        const int q = (p << 8) + tid;
        const int row = q >> 3, kc = (q & 7) << 2;
        const float4 v = *(const float4*)&node[(long)(rowb + row)*HH + k0 + kc];
        f16x4 hv; hv[0] = f2h(v.x); hv[1] = f2h(v.y); hv[2] = f2h(v.z); hv[3] = f2h(v.w);
        *(f16x4*)&As[(row << 5) + kc] = hv;
      }
    } else {
      // A from msgs f16
      #pragma unroll
      for (int p = 0; p < 2; p++) {
        const int q = (p << 8) + tid;
        const int row = q >> 2, ks = (q & 3) << 3;
        *(uint4*)&As[(row << 5) + ks] =
            *(const uint4*)&msgs[(long)(rowb + row)*HH + (k0 - HH) + ks];
      }
    }
    // B from Wupd f16 [128][256]
    #pragma unroll
    for (int p = 0; p < 2; p++) {
      const int q = (p << 8) + tid;
      const int row = q >> 2, ks = (q & 3) << 3;
      *(uint4*)&Bs[(row << 5) + ks] = *(const uint4*)&Wupd[(long)row*256 + k0 + ks];
    }
    __syncthreads();
    f16x8 af[4], bf[4];
    #pragma unroll
    for (int i = 0; i < 4; i++) {
      af[i] = *(const f16x8*)&As[((wm + (i << 4) + (lane & 15)) << 5) + ((lane >> 4) << 3)];
      bf[i] = *(const f16x8*)&Bs[((wn + (i << 4) + (lane & 15)) << 5) + ((lane >> 4) << 3)];
    }
    #pragma unroll
    for (int i = 0; i < 4; i++)
      #pragma unroll
      for (int j = 0; j < 4; j++)
        acc[i][j] = __builtin_amdgcn_mfma_f32_16x16x32_f16(af[i], bf[j], acc[i][j], 0, 0, 0);
    __syncthreads();
  }

  const int rb = (lane >> 4) << 2, cb = lane & 15;
  float bup[4], s[4] = {0,0,0,0}, qq[4] = {0,0,0,0};
  #pragma unroll
  for (int j = 0; j < 4; j++) bup[j] = b_upd[wn + (j << 4) + cb];
  #pragma unroll
  for (int i = 0; i < 4; i++)
    #pragma unroll
    for (int r = 0; r < 4; r++) {
      const int gm = rowb + wm + (i << 4) + rb + r;             // flat row
      #pragma unroll
      for (int j = 0; j < 4; j++) {
        const int gn = wn + (j << 4) + cb;                      // o
        const float v = fmaxf(acc[i][j][r] + bup[j], 0.f);
        upd[(long)gm*HH + gn] = f2h(v);
        s[j] += v; qq[j] += v*v;
      }
    }
  #pragma unroll
  for (int j = 0; j < 4; j++) {
    const int gn = wn + (j << 4) + cb;
    atomicAdd(&colS[gn], s[j]);
    atomicAdd(&colQ[gn], qq[j]);
  }
  __syncthreads();
  if (tid < 128) {
    atomicAdd(&sums[tid],       colS[tid]);
    atomicAdd(&sums[128 + tid], colQ[tid]);
  }
}

// ---------------------------------------------------------------------------
__global__ __launch_bounds__(256) void final_k(const f16* __restrict__ upd,
    const float* __restrict__ node, const float* __restrict__ sums,
    const float* __restrict__ gamma, const float* __restrict__ beta,
    float* __restrict__ out)
{
  const long idx = (long)blockIdx.x*256 + threadIdx.x;   // float4 index
  const f16x4 u  = *(const f16x4*)&upd[idx << 2];
  const float4 nd = ((const float4*)node)[idx];
  const int ob = (idx & 31) << 2;
  const float inv = 1.0f/32768.0f;
  float4 res;
  #pragma unroll
  for (int c = 0; c < 4; c++) {
    const float m  = sums[ob + c]*inv;
    const float va = sums[128 + ob + c]*inv - m*m;
    const float sc = rsqrtf(va + EPS)*gamma[ob + c];
    ((float*)&res)[c] = ((float)u[c] - m)*sc + beta[ob + c]
                      + ((const float*)&nd)[c];
  }
  ((float4*)out)[idx] = res;
}

// ---------------------------------------------------------------------------
extern "C" void kernel_launch(void* const* d_in, const int* in_sizes, int n_in,
                              void* d_out, int out_size, void* d_ws, size_t ws_size,
                              hipStream_t stream) {
  const float* node  = (const float*)d_in[0];
  const float* E     = (const float*)d_in[1];
  const int*   adj   = (const int*)  d_in[2];
  const float* W_msg = (const float*)d_in[3];
  const float* b_msg = (const float*)d_in[4];
  const float* W_upd = (const float*)d_in[5];
  const float* b_upd = (const float*)d_in[6];
  const float* gamma = (const float*)d_in[7];
  const float* beta  = (const float*)d_in[8];
  float* out = (float*)d_out;

  char* p = (char*)d_ws;
  auto alloc = [&](size_t n) { void* r = (void*)p; p += (n + 255) & ~(size_t)255; return r; };
  f16*   h_part_T = (f16*)  alloc((size_t)BB*HH*NN*2);   // [b][o][i]  8 MB
  f16*   msgs     = (f16*)  alloc((size_t)ROWS*HH*2);    // [row][o]   8 MB
  f16*   upd      = (f16*)  alloc((size_t)ROWS*HH*2);    // relu out   8 MB
  float* e_agg    = (float*)alloc((size_t)BB*NN*3*4);    // 384 KB
  f16*   Wh       = (f16*)  alloc((size_t)HH*HH*2);
  f16*   Wupd     = (f16*)  alloc((size_t)HH*256*2);
  float* We       = (float*)alloc((size_t)HH*3*4);
  float* deg      = (float*)alloc((size_t)NN*4);
  float* sums     = (float*)alloc((size_t)256*4);

  prep0_k<<<7, 256, 0, stream>>>(W_msg, W_upd, Wh, Wupd, We, e_agg, deg, sums);

  phaseB_k<<<1280, 256, 0, stream>>>(node, E, adj, Wh, h_part_T, e_agg, deg);

  gemm1_k<<<dim3(8, 1, BB), 256, 0, stream>>>(adj, h_part_T, deg, b_msg, e_agg, We, msgs);

  gemm2_k<<<256, 256, 0, stream>>>(node, msgs, Wupd, b_upd, upd, sums);

  final_k<<<4096, 256, 0, stream>>>(upd, node, sums, gamma, beta, out);
}